// Round 1
// baseline (183.750 us; speedup 1.0000x reference)
//
#include <hip/hip_runtime.h>

// out[i] = floor(image[i] * 0.5f) — pure elementwise stream, memory-bound.
// image: 8*3*1024*1024 fp32 (25,165,824 elements). Compulsory traffic:
// 96 MiB read + 96 MiB write = 192 MiB — which FITS the 256 MiB Infinity
// Cache. The benchmark replays the same graph repeatedly, so we WANT this
// working set cached in LLC: plain cached loads/stores (no nontemporal
// hints — nt bypasses L2/L3 and forces every replay to HBM).

typedef float vfloat4 __attribute__((ext_vector_type(4)));

__device__ __forceinline__ vfloat4 halve_floor4(vfloat4 v) {
    vfloat4 r;
    r.x = floorf(v.x * 0.5f);
    r.y = floorf(v.y * 0.5f);
    r.z = floorf(v.z * 0.5f);
    r.w = floorf(v.w * 0.5f);
    return r;
}

__global__ __launch_bounds__(256) void stego_halve(const float* __restrict__ in,
                                                   float* __restrict__ out,
                                                   int n4, int n) {
    const int stride = gridDim.x * blockDim.x;
    const int tid = blockIdx.x * blockDim.x + threadIdx.x;
    const vfloat4* __restrict__ in4 = (const vfloat4*)in;
    vfloat4* __restrict__ out4 = (vfloat4*)out;

    int i = tid;
    // Fast path: 4 strided float4s per round; the 4 loads are issued
    // back-to-back (no intervening stores) for memory-level parallelism,
    // then the 4 stores. Grid = 2048 blocks (8/CU, exactly resident) means
    // each thread runs this round 3x for the bench shape (12 float4/thread).
    for (; i + 3 * stride < n4; i += 4 * stride) {
        vfloat4 v0 = in4[i];
        vfloat4 v1 = in4[i + stride];
        vfloat4 v2 = in4[i + 2 * stride];
        vfloat4 v3 = in4[i + 3 * stride];
        out4[i]              = halve_floor4(v0);
        out4[i + stride]     = halve_floor4(v1);
        out4[i + 2 * stride] = halve_floor4(v2);
        out4[i + 3 * stride] = halve_floor4(v3);
    }
    // Remainder float4s (none for the bench shape with this grid).
    for (; i < n4; i += stride) {
        out4[i] = halve_floor4(in4[i]);
    }
    // Scalar tail (<4 elements; none for the bench shape).
    int t = n4 * 4 + tid;
    if (t < n) {
        out[t] = floorf(in[t] * 0.5f);
    }
}

extern "C" void kernel_launch(void* const* d_in, const int* in_sizes, int n_in,
                              void* d_out, int out_size, void* d_ws, size_t ws_size,
                              hipStream_t stream) {
    const float* image = (const float*)d_in[0];
    float* out = (float*)d_out;
    int n = in_sizes[0];   // 25,165,824

    int n4 = n / 4;        // 6,291,456 float4s

    const int block = 256;
    // 4 float4s per fast-path round; cap at 2048 blocks (8 blocks/CU on
    // 256 CUs = exactly-resident) and grid-stride the rest (G11).
    long long threads_needed = ((long long)n4 + 3) / 4;
    if (threads_needed < 1) threads_needed = 1;
    int grid = (int)((threads_needed + block - 1) / block);
    if (grid > 2048) grid = 2048;
    if (grid < 1) grid = 1;

    stego_halve<<<grid, block, 0, stream>>>(image, out, n4, n);
}

// Round 2
// 166.462 us; speedup vs baseline: 1.1039x; 1.1039x over previous
//
#include <hip/hip_runtime.h>

// out[i] = floor(image[i] * 0.5f) — pure elementwise stream, memory-bound.
// image: 8*3*1024*1024 fp32 (25,165,824 elements = 6,291,456 float4s).
// Compulsory traffic: 96 MiB read + 96 MiB write = 192 MiB → ~30 µs @ 6.3 TB/s.
//
// Harness anatomy (decoded from rocprof): each timed iteration = two 384 MiB
// poison fills (~120 µs, harness-owned, thrashes the 256 MiB LLC) + this
// kernel. So LLC residency across replays is impossible; the data is a pure
// one-shot stream -> nontemporal (evict-first) loads AND stores.
//
// Kernel shape: monolithic one-float4-per-thread, no loop — the same shape as
// the 6.8 TB/s fill kernel and the m13 6.29 TB/s copy µbench. 24,576 blocks
// of 256; every load is independent (max TLP, zero loop overhead).
//
// NOTE: __builtin_nontemporal_* rejects HIP_vector_type structs; use a native
// clang ext_vector_type float4 (identical 16B layout/alignment).

typedef float vfloat4 __attribute__((ext_vector_type(4)));

__global__ __launch_bounds__(256) void stego_halve(const vfloat4* __restrict__ in,
                                                   vfloat4* __restrict__ out,
                                                   int n4) {
    int i = blockIdx.x * 256 + threadIdx.x;
    if (i < n4) {
        vfloat4 v = __builtin_nontemporal_load(&in[i]);
        vfloat4 r;
        r.x = floorf(v.x * 0.5f);
        r.y = floorf(v.y * 0.5f);
        r.z = floorf(v.z * 0.5f);
        r.w = floorf(v.w * 0.5f);
        __builtin_nontemporal_store(r, &out[i]);
    }
}

__global__ __launch_bounds__(256) void stego_halve_tail(const float* __restrict__ in,
                                                        float* __restrict__ out,
                                                        int start, int n) {
    int i = start + blockIdx.x * 256 + threadIdx.x;
    if (i < n) {
        out[i] = floorf(in[i] * 0.5f);
    }
}

extern "C" void kernel_launch(void* const* d_in, const int* in_sizes, int n_in,
                              void* d_out, int out_size, void* d_ws, size_t ws_size,
                              hipStream_t stream) {
    const float* image = (const float*)d_in[0];
    float* out = (float*)d_out;
    int n = in_sizes[0];   // 25,165,824

    int n4 = n / 4;        // 6,291,456 float4s
    int tail_start = n4 * 4;

    if (n4 > 0) {
        const int block = 256;
        int grid = (n4 + block - 1) / block;   // 24,576 for the bench shape
        stego_halve<<<grid, block, 0, stream>>>((const vfloat4*)image,
                                                (vfloat4*)out, n4);
    }
    if (tail_start < n) {
        int rem = n - tail_start;
        const int block = 256;
        int grid = (rem + block - 1) / block;
        stego_halve_tail<<<grid, block, 0, stream>>>(image, out, tail_start, n);
    }
}